// Round 19
// baseline (14278.729 us; speedup 1.0000x reference)
//
#include <hip/hip_runtime.h>
#include <hip/hip_cooperative_groups.h>
#include <cstdint>
#include <cstddef>

// ====================================================================
// PyroSimpleSpeakerListenerLSTM — Round 19.
// r18 cooperative launch failed (LDS 160KB/CU exact -> 4 blocks/CU
// infeasible -> launch rejected -> decoder skipped). Fixes:
//  * LDS rows 40->36 shorts (147KB/CU, 16KB headroom; 2-way conflicts)
//  * host fallback: if cooperative launch errors, run the r17-style
//    per-step loop (bit-identical math on both paths).
// Kernels _r19.
// ====================================================================

namespace cg = cooperative_groups;

namespace {

constexpr int MZ = 512;
constexpr int EMB = 256;
constexpr int H = 512;
constexpr int SL = 32;
constexpr int BT = 16;
constexpr int AR = 64;
constexpr int GG = 4 * H;
constexpr int RD = BT * MZ;
constexpr int LROW = 36;     // padded LDS row (shorts): 72B
constexpr int SAMP_BLOCKS = 128;
constexpr int MFMA_BLOCKS = (H / 32) * (RD / 128);   // 1024

typedef float f32x4 __attribute__((ext_vector_type(4)));
typedef __bf16 bf16x8 __attribute__((ext_vector_type(8)));

struct KK { unsigned a, b; };

__host__ __device__ constexpr unsigned rotl32(unsigned v, int r) {
  return (v << r) | (v >> (32 - r));
}

__host__ __device__ constexpr KK tf(unsigned k0, unsigned k1, unsigned x0, unsigned x1) {
  unsigned k2 = k0 ^ k1 ^ 0x1BD11BDAu;
  x0 += k0; x1 += k1;
  x0 += x1; x1 = rotl32(x1,13); x1 ^= x0;
  x0 += x1; x1 = rotl32(x1,15); x1 ^= x0;
  x0 += x1; x1 = rotl32(x1,26); x1 ^= x0;
  x0 += x1; x1 = rotl32(x1, 6); x1 ^= x0;
  x0 += k1; x1 += k2 + 1u;
  x0 += x1; x1 = rotl32(x1,17); x1 ^= x0;
  x0 += x1; x1 = rotl32(x1,29); x1 ^= x0;
  x0 += x1; x1 = rotl32(x1,16); x1 ^= x0;
  x0 += x1; x1 = rotl32(x1,24); x1 ^= x0;
  x0 += k2; x1 += k0 + 2u;
  x0 += x1; x1 = rotl32(x1,13); x1 ^= x0;
  x0 += x1; x1 = rotl32(x1,15); x1 ^= x0;
  x0 += x1; x1 = rotl32(x1,26); x1 ^= x0;
  x0 += x1; x1 = rotl32(x1, 6); x1 ^= x0;
  x0 += k0; x1 += k1 + 3u;
  x0 += x1; x1 = rotl32(x1,17); x1 ^= x0;
  x0 += x1; x1 = rotl32(x1,29); x1 ^= x0;
  x0 += x1; x1 = rotl32(x1,16); x1 ^= x0;
  x0 += x1; x1 = rotl32(x1,24); x1 ^= x0;
  x0 += k1; x1 += k2 + 4u;
  x0 += x1; x1 = rotl32(x1,13); x1 ^= x0;
  x0 += x1; x1 = rotl32(x1,15); x1 ^= x0;
  x0 += x1; x1 = rotl32(x1,26); x1 ^= x0;
  x0 += x1; x1 = rotl32(x1, 6); x1 ^= x0;
  x0 += k2; x1 += k0 + 5u;
  return KK{x0, x1};
}

constexpr KK KEYA = tf(0u, 42u, 0u, 0u);
constexpr KK KEYB = tf(0u, 42u, 0u, 1u);

__device__ __forceinline__ void split2(KK k, KK& o0, KK& o1) {
  o0 = tf(k.a, k.b, 0u, 0u); o1 = tf(k.a, k.b, 0u, 1u);
}

__device__ __forceinline__ void split3(KK k, KK& o0, KK& o1, KK& o2) {
  o0 = tf(k.a, k.b, 0u, 0u); o1 = tf(k.a, k.b, 0u, 1u); o2 = tf(k.a, k.b, 0u, 2u);
}

__device__ __forceinline__ KK elem_key(KK gk, unsigned j) {
  return tf(gk.a, gk.b, 0u, j);
}

__device__ __forceinline__ unsigned rb32(KK k) {
  KK r = tf(k.a, k.b, 0u, 0u);
  return r.a ^ r.b;
}

__device__ __forceinline__ float u01_from_bits(unsigned bits) {
  return __uint_as_float(0x3F800000u | (bits >> 9)) - 1.0f;
}
__device__ __forceinline__ float uniform01(KK k) {
  return u01_from_bits(rb32(k));
}

__device__ float erfinv_xla(float x) {
  float xx = __fmul_rn(x, x);
  float w = -log1pf(-xx);
  float p;
  if (w < 5.0f) {
    w = __fsub_rn(w, 2.5f);
    p = 2.81022636e-08f;
    p = __fadd_rn(3.43273939e-07f, __fmul_rn(p, w));
    p = __fadd_rn(-3.5233877e-06f, __fmul_rn(p, w));
    p = __fadd_rn(-4.39150654e-06f, __fmul_rn(p, w));
    p = __fadd_rn(0.00021858087f, __fmul_rn(p, w));
    p = __fadd_rn(-0.00125372503f, __fmul_rn(p, w));
    p = __fadd_rn(-0.00417768164f, __fmul_rn(p, w));
    p = __fadd_rn(0.246640727f, __fmul_rn(p, w));
    p = __fadd_rn(1.50140941f, __fmul_rn(p, w));
  } else {
    w = __fsub_rn(__fsqrt_rn(w), 3.0f);
    p = -0.000200214257f;
    p = __fadd_rn(0.000100950558f, __fmul_rn(p, w));
    p = __fadd_rn(0.00134934322f, __fmul_rn(p, w));
    p = __fadd_rn(-0.00367342844f, __fmul_rn(p, w));
    p = __fadd_rn(0.00573950773f, __fmul_rn(p, w));
    p = __fadd_rn(-0.0076224613f, __fmul_rn(p, w));
    p = __fadd_rn(0.00943887047f, __fmul_rn(p, w));
    p = __fadd_rn(1.00167406f, __fmul_rn(p, w));
    p = __fadd_rn(2.83297682f, __fmul_rn(p, w));
  }
  return __fmul_rn(p, x);
}

__device__ __forceinline__ float normal_f(KK k) {
  float f = u01_from_bits(rb32(k));
  const float lo = __uint_as_float(0xBF7FFFFFu);
  float u = __fadd_rn(__fmul_rn(f, 2.0f), lo);
  u = fmaxf(lo, u);
  return __fmul_rn(__uint_as_float(0x3FB504F3u), erfinv_xla(u));
}

__device__ float loggamma_one(KK ekey, float alpha_orig) {
  KK key, sub;
  split2(ekey, key, sub);
  float u_boost = uniform01(sub);
  const bool boost = (alpha_orig >= 1.0f);
  const float al = boost ? alpha_orig : __fadd_rn(alpha_orig, 1.0f);
  const float third = (float)(1.0 / 3.0);
  const float d = __fsub_rn(al, third);
  const float c = __fdiv_rn(third, __fsqrt_rn(d));
  float X, V;
  for (;;) {
    KK nk, xk, uk;
    split3(key, nk, xk, uk);
    key = nk;
    float x, v;
    KK kk = xk;
    do {
      KK k2, ns;
      split2(kk, k2, ns);
      kk = k2;
      x = normal_f(ns);
      v = __fadd_rn(1.0f, __fmul_rn(x, c));
    } while (v <= 0.0f);
    X = __fmul_rn(x, x);
    V = __fmul_rn(__fmul_rn(v, v), v);
    float U = uniform01(uk);
    float sq = __fsub_rn(1.0f, __fmul_rn(0.0331f, __fmul_rn(X, X)));
    if (U < sq) break;
    float rhs = __fadd_rn(__fmul_rn(0.5f, X),
                          __fmul_rn(d, __fadd_rn(__fsub_rn(1.0f, V), logf(V))));
    if (logf(U) < rhs) break;
  }
  float ls = __fadd_rn(logf(d), logf(V));
  if (!boost)
    ls = __fadd_rn(ls, __fdiv_rn(log1pf(-u_boost), alpha_orig));
  return ls;
}

__device__ __forceinline__ float sigm(float x) { return 1.0f / (1.0f + expf(-x)); }

__device__ __forceinline__ unsigned short f2bf(float x) {
  unsigned u = __float_as_uint(x);
  unsigned r = (u + 0x7fffu + ((u >> 16) & 1u)) >> 16;
  return (unsigned short)r;
}
__device__ __forceinline__ float bf2f(unsigned short h) {
  return __uint_as_float(((unsigned)h) << 16);
}
__device__ __forceinline__ void split_bf(float x, unsigned short& hi, unsigned short& lo) {
  hi = f2bf(x);
  lo = f2bf(x - bf2f(hi));
}

__device__ __forceinline__ void beta_sample(const float* __restrict__ alphaA,
                                            const float* __restrict__ betaA,
                                            unsigned short* __restrict__ sigHi,
                                            unsigned short* __restrict__ sigLo,
                                            unsigned idx, int s) {
  unsigned r = idx >> 6;
  unsigned j = idx & 63u;
  unsigned b = r >> 9;
  unsigned m = r & 511u;
  size_t ab = ((size_t)s * MZ + m) * AR + j;
  float alpha = alphaA[ab];
  float beta = betaA[ab];
  unsigned jl = ((b * 32u + (unsigned)s) * 512u + m) * 64u + j;
  float lga = loggamma_one(elem_key(KEYA, jl), alpha);
  float lgb = loggamma_one(elem_key(KEYB, jl), beta);
  float lm = fmaxf(lga, lgb);
  float ea = expf(__fsub_rn(lga, lm));
  float eb = expf(__fsub_rn(lgb, lm));
  float sv = __fdiv_rn(ea, __fadd_rn(ea, eb));
  split_bf(sv, sigHi[idx], sigLo[idx]);
}

// shared inner body: stage k-tile + 12 MFMAs (identical math both paths)
struct StepPtrs {
  const unsigned short *sHi, *sLo, *hInHi, *hInLo;
};

} // namespace

// ----------------------------- kernels ------------------------------

__global__ __launch_bounds__(256) void fill_sentinel_r19(float* o, int n) {
  int i = blockIdx.x * 256 + threadIdx.x;
  if (i < n) o[i] = 12345.0f;
}

__global__ __launch_bounds__(256) void init_states_r19(const float* __restrict__ encI,
                                                       const float* __restrict__ decI,
                                                       float* __restrict__ hE, float* __restrict__ cE,
                                                       float* __restrict__ hD, float* __restrict__ cD) {
  int idx = blockIdx.x * 256 + threadIdx.x;
  int u = idx & (H - 1);
  if (idx < MZ * H) { hE[idx] = encI[u]; cE[idx] = encI[H + u]; }
  hD[idx] = decI[u]; cD[idx] = decI[H + u];
}

__global__ __launch_bounds__(256) void prep_dec_r19(const float* __restrict__ Wih,
                                                    const float* __restrict__ Whh,
                                                    const float* __restrict__ b1,
                                                    const float* __restrict__ b2,
                                                    unsigned short* __restrict__ WihHi,
                                                    unsigned short* __restrict__ WihLo,
                                                    unsigned short* __restrict__ WhhHi,
                                                    unsigned short* __restrict__ WhhLo,
                                                    float* __restrict__ bsum,
                                                    const float* __restrict__ hD,
                                                    unsigned short* __restrict__ hHi,
                                                    unsigned short* __restrict__ hLo) {
  int idx = blockIdx.x * 256 + threadIdx.x;   // GG*H threads
  split_bf(Whh[idx], WhhHi[idx], WhhLo[idx]);
  if (idx < GG * AR) split_bf(Wih[idx], WihHi[idx], WihLo[idx]);
  if (idx < GG) bsum[idx] = b1[idx] + b2[idx];
  for (int i = idx; i < RD * H; i += GG * H) split_bf(hD[i], hHi[i], hLo[i]);
}

template <int MODE>
__global__ __launch_bounds__(256) void gemm_abt_r19(const float* __restrict__ A,
                                                    const float* __restrict__ B,
                                                    float* __restrict__ C,
                                                    const float* __restrict__ X1,
                                                    const float* __restrict__ X2,
                                                    int M, int N, int K) {
  __shared__ float As[16][68];
  __shared__ float Bs[16][68];
  int tid = threadIdx.x;
  int tx = tid & 15, ty = tid >> 4;
  int n0 = blockIdx.x * 64, m0 = blockIdx.y * 64;
  int lr = tid >> 2, lk4 = (tid & 3) * 4;
  float acc[4][4] = {};
  for (int k0 = 0; k0 < K; k0 += 16) {
    float4 a4 = *reinterpret_cast<const float4*>(A + (size_t)(m0 + lr) * K + k0 + lk4);
    float4 b4 = *reinterpret_cast<const float4*>(B + (size_t)(n0 + lr) * K + k0 + lk4);
    __syncthreads();
    As[lk4 + 0][lr] = a4.x; As[lk4 + 1][lr] = a4.y; As[lk4 + 2][lr] = a4.z; As[lk4 + 3][lr] = a4.w;
    Bs[lk4 + 0][lr] = b4.x; Bs[lk4 + 1][lr] = b4.y; Bs[lk4 + 2][lr] = b4.z; Bs[lk4 + 3][lr] = b4.w;
    __syncthreads();
#pragma unroll
    for (int k = 0; k < 16; ++k) {
      float av[4], bv[4];
#pragma unroll
      for (int i = 0; i < 4; ++i) av[i] = As[k][ty * 4 + i];
#pragma unroll
      for (int j = 0; j < 4; ++j) bv[j] = Bs[k][tx * 4 + j];
#pragma unroll
      for (int i = 0; i < 4; ++i)
#pragma unroll
        for (int j = 0; j < 4; ++j) acc[i][j] = fmaf(av[i], bv[j], acc[i][j]);
    }
  }
#pragma unroll
  for (int i = 0; i < 4; ++i) {
    int m = m0 + ty * 4 + i;
#pragma unroll
    for (int j = 0; j < 4; ++j) {
      int n = n0 + tx * 4 + j;
      float v = acc[i][j];
      if (MODE == 1) v += X1[n] + X2[n];
      if (MODE == 2) v += X1[(size_t)m * N + n];
      C[(size_t)m * N + n] = v;
    }
  }
}

// --- persistent cooperative decoder (primary path) ---
__global__ __launch_bounds__(256, 4) void dec_persist_r19(
    unsigned short* sig0Hi, unsigned short* sig0Lo,
    unsigned short* sig1Hi, unsigned short* sig1Lo,
    unsigned short* h0Hi, unsigned short* h0Lo,
    unsigned short* h1Hi, unsigned short* h1Lo,
    const unsigned short* __restrict__ WihHi, const unsigned short* __restrict__ WihLo,
    const unsigned short* __restrict__ WhhHi, const unsigned short* __restrict__ WhhLo,
    const float* __restrict__ bsum, float* __restrict__ hD,
    const float* __restrict__ cInit,
    const float* __restrict__ alphaA, const float* __restrict__ betaA) {
  __shared__ __align__(16) unsigned short AhiS[128 * LROW];
  __shared__ __align__(16) unsigned short AloS[128 * LROW];
  __shared__ __align__(16) unsigned short BhiS[128 * LROW];
  __shared__ __align__(16) unsigned short BloS[128 * LROW];
  cg::grid_group grid = cg::this_grid();
  int bid = blockIdx.x;
  int xcd = bid & 7, idxx = bid >> 3;
  int mb = xcd * 8 + (idxx >> 4);
  int ub = idxx & 15;
  int mbBase = mb * 128;
  int ubBase = ub * 32;
  int tid = threadIdx.x;
  int lane = tid & 63, wid = tid >> 6;
  int wr = wid >> 1, wu = wid & 1;
  int lr = lane & 15;
  int lk = (lane >> 4) * 8;
  int srow = tid >> 2;
  int scol = (tid & 3) * 8;
  int m0 = mbBase + wr * 64;
  int crow = (lane >> 4) * 4;
  int u = ubBase + wu * 16 + (lane & 15);
  float bi = bsum[u], bff = bsum[u + 512], bg = bsum[u + 1024], bo = bsum[u + 1536];
  float creg[4][4];
  {
    float c0 = cInit[u];
#pragma unroll
    for (int i = 0; i < 4; ++i)
#pragma unroll
      for (int r = 0; r < 4; ++r) creg[i][r] = c0;
  }
  for (int s = 0; s < SL; ++s) {
    const unsigned short *sHi, *sLo, *hInHi, *hInLo;
    unsigned short *hOutHi, *hOutLo, *snHi, *snLo;
    if (s & 1) {
      sHi = sig1Hi; sLo = sig1Lo; hInHi = h1Hi; hInLo = h1Lo;
      hOutHi = h0Hi; hOutLo = h0Lo; snHi = sig0Hi; snLo = sig0Lo;
    } else {
      sHi = sig0Hi; sLo = sig0Lo; hInHi = h0Hi; hInLo = h0Lo;
      hOutHi = h1Hi; hOutLo = h1Lo; snHi = sig1Hi; snLo = sig1Lo;
    }
    if (s < SL - 1) {
      unsigned base = (unsigned)bid * 256 + tid;
      beta_sample(alphaA, betaA, snHi, snLo, base, s + 1);
      beta_sample(alphaA, betaA, snHi, snLo, base + 262144u, s + 1);
    }
    f32x4 acc[4][4] = {};
    for (int ks = 0; ks < 18; ++ks) {
      int k0 = ks * 32;
      const unsigned short* Ah; const unsigned short* Al;
      const unsigned short* Bh; const unsigned short* Bl;
      int K, kk;
      if (k0 < 64) { Ah = sHi; Al = sLo; Bh = WihHi; Bl = WihLo; K = AR; kk = k0; }
      else         { Ah = hInHi; Al = hInLo; Bh = WhhHi; Bl = WhhLo; K = H; kk = k0 - 64; }
      __syncthreads();
#pragma unroll
      for (int q = 0; q < 2; ++q) {
        int row = q * 64 + srow;
        size_t asrc = (size_t)(mbBase + row) * K + kk + scol;
        int g = row >> 5, uu = row & 31;
        size_t bsrc = (size_t)(g * 512 + ubBase + uu) * K + kk + scol;
        int ldst = row * LROW + scol;
        *reinterpret_cast<bf16x8*>(&AhiS[ldst]) = *reinterpret_cast<const bf16x8*>(Ah + asrc);
        *reinterpret_cast<bf16x8*>(&AloS[ldst]) = *reinterpret_cast<const bf16x8*>(Al + asrc);
        *reinterpret_cast<bf16x8*>(&BhiS[ldst]) = *reinterpret_cast<const bf16x8*>(Bh + bsrc);
        *reinterpret_cast<bf16x8*>(&BloS[ldst]) = *reinterpret_cast<const bf16x8*>(Bl + bsrc);
      }
      __syncthreads();
      bf16x8 ah[4], al[4], bh[4], bl[4];
#pragma unroll
      for (int f = 0; f < 4; ++f) {
        int arow = wr * 64 + f * 16 + lr;
        ah[f] = *reinterpret_cast<const bf16x8*>(&AhiS[arow * LROW + lk]);
        al[f] = *reinterpret_cast<const bf16x8*>(&AloS[arow * LROW + lk]);
        int brow = f * 32 + wu * 16 + lr;
        bh[f] = *reinterpret_cast<const bf16x8*>(&BhiS[brow * LROW + lk]);
        bl[f] = *reinterpret_cast<const bf16x8*>(&BloS[brow * LROW + lk]);
      }
#pragma unroll
      for (int i = 0; i < 4; ++i)
#pragma unroll
        for (int g = 0; g < 4; ++g) {
          acc[i][g] = __builtin_amdgcn_mfma_f32_16x16x32_bf16(ah[i], bh[g], acc[i][g], 0, 0, 0);
          acc[i][g] = __builtin_amdgcn_mfma_f32_16x16x32_bf16(ah[i], bl[g], acc[i][g], 0, 0, 0);
          acc[i][g] = __builtin_amdgcn_mfma_f32_16x16x32_bf16(al[i], bh[g], acc[i][g], 0, 0, 0);
        }
    }
#pragma unroll
    for (int i = 0; i < 4; ++i) {
#pragma unroll
      for (int r = 0; r < 4; ++r) {
        int m = m0 + i * 16 + crow + r;
        size_t idx = (size_t)m * H + u;
        float gi = acc[i][0][r] + bi;
        float gf = acc[i][1][r] + bff;
        float gg = acc[i][2][r] + bg;
        float go = acc[i][3][r] + bo;
        float cn = sigm(gf) * creg[i][r] + sigm(gi) * tanhf(gg);
        float hn = sigm(go) * tanhf(cn);
        creg[i][r] = cn;
        if (s == SL - 1) hD[idx] = hn;
        split_bf(hn, hOutHi[idx], hOutLo[idx]);
      }
    }
    __threadfence();
    grid.sync();
  }
}

// --- fallback: r17-style per-step merged kernel (identical math) ---
__global__ __launch_bounds__(256) void mfma_step_r19(
    const unsigned short* __restrict__ sigHi, const unsigned short* __restrict__ sigLo,
    const unsigned short* __restrict__ hHiIn, const unsigned short* __restrict__ hLoIn,
    const unsigned short* __restrict__ WihHi, const unsigned short* __restrict__ WihLo,
    const unsigned short* __restrict__ WhhHi, const unsigned short* __restrict__ WhhLo,
    const float* __restrict__ bsum,
    float* __restrict__ hD, float* __restrict__ cD,
    unsigned short* __restrict__ hHiOut, unsigned short* __restrict__ hLoOut,
    int writeHF,
    const float* __restrict__ alphaA, const float* __restrict__ betaA,
    unsigned short* __restrict__ sigHiNext, unsigned short* __restrict__ sigLoNext,
    int sNext, int nSamp) {
  __shared__ __align__(16) unsigned short AhiS[128 * LROW];
  __shared__ __align__(16) unsigned short AloS[128 * LROW];
  __shared__ __align__(16) unsigned short BhiS[128 * LROW];
  __shared__ __align__(16) unsigned short BloS[128 * LROW];
  int bid = blockIdx.x;
  if (bid < nSamp) {
    unsigned base = bid * 256 + threadIdx.x;
    unsigned stride = (unsigned)nSamp * 256;
    for (unsigned idx = base; idx < (unsigned)(RD * AR); idx += stride)
      beta_sample(alphaA, betaA, sigHiNext, sigLoNext, idx, sNext);
    return;
  }
  bid -= nSamp;
  int ub = bid & 15;
  int mb = bid >> 4;
  int mbBase = mb * 128;
  int ubBase = ub * 32;
  int tid = threadIdx.x;
  int lane = tid & 63, wid = tid >> 6;
  int wr = wid >> 1, wu = wid & 1;
  int lr = lane & 15;
  int lk = (lane >> 4) * 8;
  int srow = tid >> 2;
  int scol = (tid & 3) * 8;
  f32x4 acc[4][4] = {};
  for (int ks = 0; ks < 18; ++ks) {
    int k0 = ks * 32;
    const unsigned short* Ah; const unsigned short* Al;
    const unsigned short* Bh; const unsigned short* Bl;
    int K, kk;
    if (k0 < 64) { Ah = sigHi; Al = sigLo; Bh = WihHi; Bl = WihLo; K = AR; kk = k0; }
    else         { Ah = hHiIn; Al = hLoIn; Bh = WhhHi; Bl = WhhLo; K = H;  kk = k0 - 64; }
    __syncthreads();
#pragma unroll
    for (int q = 0; q < 2; ++q) {
      int row = q * 64 + srow;
      size_t asrc = (size_t)(mbBase + row) * K + kk + scol;
      int g = row >> 5, uu = row & 31;
      size_t bsrc = (size_t)(g * 512 + ubBase + uu) * K + kk + scol;
      int ldst = row * LROW + scol;
      *reinterpret_cast<bf16x8*>(&AhiS[ldst]) = *reinterpret_cast<const bf16x8*>(Ah + asrc);
      *reinterpret_cast<bf16x8*>(&AloS[ldst]) = *reinterpret_cast<const bf16x8*>(Al + asrc);
      *reinterpret_cast<bf16x8*>(&BhiS[ldst]) = *reinterpret_cast<const bf16x8*>(Bh + bsrc);
      *reinterpret_cast<bf16x8*>(&BloS[ldst]) = *reinterpret_cast<const bf16x8*>(Bl + bsrc);
    }
    __syncthreads();
    bf16x8 ah[4], al[4], bh[4], bl[4];
#pragma unroll
    for (int f = 0; f < 4; ++f) {
      int arow = wr * 64 + f * 16 + lr;
      ah[f] = *reinterpret_cast<const bf16x8*>(&AhiS[arow * LROW + lk]);
      al[f] = *reinterpret_cast<const bf16x8*>(&AloS[arow * LROW + lk]);
      int brow = f * 32 + wu * 16 + lr;
      bh[f] = *reinterpret_cast<const bf16x8*>(&BhiS[brow * LROW + lk]);
      bl[f] = *reinterpret_cast<const bf16x8*>(&BloS[brow * LROW + lk]);
    }
#pragma unroll
    for (int i = 0; i < 4; ++i)
#pragma unroll
      for (int g = 0; g < 4; ++g) {
        acc[i][g] = __builtin_amdgcn_mfma_f32_16x16x32_bf16(ah[i], bh[g], acc[i][g], 0, 0, 0);
        acc[i][g] = __builtin_amdgcn_mfma_f32_16x16x32_bf16(ah[i], bl[g], acc[i][g], 0, 0, 0);
        acc[i][g] = __builtin_amdgcn_mfma_f32_16x16x32_bf16(al[i], bh[g], acc[i][g], 0, 0, 0);
      }
  }
  int m0 = mbBase + wr * 64;
  int crow = (lane >> 4) * 4;
  int u = ubBase + wu * 16 + (lane & 15);
  float bi = bsum[u], bff = bsum[u + 512], bg = bsum[u + 1024], bo = bsum[u + 1536];
#pragma unroll
  for (int i = 0; i < 4; ++i) {
#pragma unroll
    for (int r = 0; r < 4; ++r) {
      int m = m0 + i * 16 + crow + r;
      size_t idx = (size_t)m * H + u;
      float gi = acc[i][0][r] + bi;
      float gf = acc[i][1][r] + bff;
      float gg = acc[i][2][r] + bg;
      float go = acc[i][3][r] + bo;
      float cn = sigm(gf) * cD[idx] + sigm(gi) * tanhf(gg);
      float hn = sigm(go) * tanhf(cn);
      cD[idx] = cn;
      if (writeHF) hD[idx] = hn;
      split_bf(hn, hHiOut[idx], hLoOut[idx]);
    }
  }
}

template <int EPI>
__global__ __launch_bounds__(256) void gemm_ab_r19(const float* __restrict__ A,
                                                   const float* __restrict__ B,
                                                   float* __restrict__ C0,
                                                   float* __restrict__ C1,
                                                   int M, int N, int K) {
  __shared__ float As[16][68];
  __shared__ float Bs[16][68];
  int tid = threadIdx.x;
  int tx = tid & 15, ty = tid >> 4;
  int n0 = blockIdx.x * 64, m0 = blockIdx.y * 64;
  int lr = tid >> 2, lk4 = (tid & 3) * 4;
  int bk = tid >> 4, bn4 = (tid & 15) * 4;
  float acc[4][4] = {};
  for (int k0 = 0; k0 < K; k0 += 16) {
    float4 a4 = *reinterpret_cast<const float4*>(A + (size_t)(m0 + lr) * K + k0 + lk4);
    float4 b4 = *reinterpret_cast<const float4*>(B + (size_t)(k0 + bk) * N + n0 + bn4);
    __syncthreads();
    As[lk4 + 0][lr] = a4.x; As[lk4 + 1][lr] = a4.y; As[lk4 + 2][lr] = a4.z; As[lk4 + 3][lr] = a4.w;
    *reinterpret_cast<float4*>(&Bs[bk][bn4]) = b4;
    __syncthreads();
#pragma unroll
    for (int k = 0; k < 16; ++k) {
      float av[4], bv[4];
#pragma unroll
      for (int i = 0; i < 4; ++i) av[i] = As[k][ty * 4 + i];
#pragma unroll
      for (int j = 0; j < 4; ++j) bv[j] = Bs[k][tx * 4 + j];
#pragma unroll
      for (int i = 0; i < 4; ++i)
#pragma unroll
        for (int j = 0; j < 4; ++j) acc[i][j] = fmaf(av[i], bv[j], acc[i][j]);
    }
  }
#pragma unroll
  for (int i = 0; i < 4; ++i) {
    size_t m = (size_t)(m0 + ty * 4 + i);
#pragma unroll
    for (int j = 0; j < 4; ++j) {
      int n = n0 + tx * 4 + j;
      float v = acc[i][j];
      if (EPI == 0) {
        C0[m * N + n] = v;
      } else {
        float sp = fmaxf(v, 0.0f) + log1pf(expf(-fabsf(v)));
        if (n & 1) C1[m * (N / 2) + (n >> 1)] = sp;
        else       C0[m * (N / 2) + (n >> 1)] = sp;
      }
    }
  }
}

__global__ __launch_bounds__(256) void lstm_update_r19(float* __restrict__ h, float* __restrict__ c,
                                                       const float* __restrict__ gates,
                                                       float* __restrict__ ysOut) {
  int idx = blockIdx.x * 256 + threadIdx.x;
  int r = idx >> 9, u = idx & (H - 1);
  const float* g = gates + (size_t)r * GG;
  float gi = g[u], gf = g[u + H], gg = g[u + 2 * H], go = g[u + 3 * H];
  float cn = sigm(gf) * c[idx] + sigm(gi) * tanhf(gg);
  float hn = sigm(go) * tanhf(cn);
  c[idx] = cn; h[idx] = hn;
  if (ysOut) ysOut[idx] = hn;
}

__global__ __launch_bounds__(256) void sample_beta_r19(const float* __restrict__ alphaA,
                                                       const float* __restrict__ betaA,
                                                       unsigned short* __restrict__ sigHi,
                                                       unsigned short* __restrict__ sigLo,
                                                       int s) {
  unsigned idx = blockIdx.x * 256 + threadIdx.x;
  beta_sample(alphaA, betaA, sigHi, sigLo, idx, s);
}

__global__ __launch_bounds__(256) void softmax_rows_r19(const float* __restrict__ L,
                                                        float* __restrict__ O) {
  __shared__ float red[8];
  int r = blockIdx.x;
  const float* row = L + (size_t)r * H;
  int t = threadIdx.x;
  float a = row[t], b = row[t + 256];
  float m = fmaxf(a, b);
#pragma unroll
  for (int o = 1; o < 64; o <<= 1) m = fmaxf(m, __shfl_xor(m, o));
  if ((t & 63) == 0) red[t >> 6] = m;
  __syncthreads();
  m = fmaxf(fmaxf(red[0], red[1]), fmaxf(red[2], red[3]));
  float e0 = expf(a - m), e1 = expf(b - m);
  float s = e0 + e1;
#pragma unroll
  for (int o = 1; o < 64; o <<= 1) s += __shfl_xor(s, o);
  if ((t & 63) == 0) red[4 + (t >> 6)] = s;
  __syncthreads();
  s = red[4] + red[5] + red[6] + red[7];
  O[(size_t)r * H + t] = e0 / s;
  O[(size_t)r * H + t + 256] = e1 / s;
}

// ----------------------------- launcher -----------------------------

extern "C" void kernel_launch(void* const* d_in, const int* in_sizes, int n_in,
                              void* d_out, int out_size, void* d_ws, size_t ws_size,
                              hipStream_t stream) {
  (void)in_sizes; (void)n_in;
  const float* embedding = (const float*)d_in[2];
  const float* eWih = (const float*)d_in[3];
  const float* eWhh = (const float*)d_in[4];
  const float* ebih = (const float*)d_in[5];
  const float* ebhh = (const float*)d_in[6];
  const float* eInit = (const float*)d_in[7];
  const float* dWih = (const float*)d_in[8];
  const float* dWhh = (const float*)d_in[9];
  const float* dbih = (const float*)d_in[10];
  const float* dbhh = (const float*)d_in[11];
  const float* dInit = (const float*)d_in[12];
  const float* Wp = (const float*)d_in[13];
  const float* Wo = (const float*)d_in[14];
  float* out = (float*)d_out;
  float* w = (float*)d_ws;

  size_t o = 0;
  float* xW     = w + o; o += (size_t)MZ * GG;
  float* hE     = w + o; o += (size_t)MZ * H;
  float* cE     = w + o; o += (size_t)MZ * H;
  float* ys     = w + o; o += (size_t)SL * MZ * H;
  float* alphaA = w + o; o += (size_t)SL * MZ * AR;
  float* betaA  = w + o; o += (size_t)SL * MZ * AR;
  float* hD     = w + o; o += (size_t)RD * H;
  float* cD     = w + o; o += (size_t)RD * H;
  float* regB   = w + o; o += (size_t)RD * GG / 4;
  float* logits = w + o; o += (size_t)RD * H;
  float* sig1F  = w + o; o += (size_t)RD * AR;
  if (ws_size < o * sizeof(float)) {
    fill_sentinel_r19<<<(out_size + 255) / 256, 256, 0, stream>>>(out, out_size);
    return;
  }

  unsigned short* sig0Hi = (unsigned short*)ys;
  unsigned short* sig0Lo = sig0Hi + (size_t)RD * AR;
  unsigned short* h0Hi  = sig0Lo + (size_t)RD * AR;
  unsigned short* h0Lo  = h0Hi + (size_t)RD * H;
  unsigned short* WihHi = h0Lo + (size_t)RD * H;
  unsigned short* WihLo = WihHi + (size_t)GG * AR;
  unsigned short* WhhHi = WihLo + (size_t)GG * AR;
  unsigned short* WhhLo = WhhHi + (size_t)GG * H;
  float* bsum = (float*)(WhhLo + (size_t)GG * H);
  unsigned short* h1Hi = (unsigned short*)regB;
  unsigned short* h1Lo = h1Hi + (size_t)RD * H;
  unsigned short* sig1Hi = (unsigned short*)sig1F;
  unsigned short* sig1Lo = sig1Hi + (size_t)RD * AR;

  init_states_r19<<<(RD * H) / 256, 256, 0, stream>>>(eInit, dInit, hE, cE, hD, cD);

  float* egates = logits;
  gemm_abt_r19<1><<<dim3(GG / 64, MZ / 64), 256, 0, stream>>>(embedding, eWih, xW, ebih, ebhh, MZ, GG, EMB);
  for (int s = 0; s < SL; ++s) {
    gemm_abt_r19<2><<<dim3(GG / 64, MZ / 64), 256, 0, stream>>>(hE, eWhh, egates, xW, nullptr, MZ, GG, H);
    lstm_update_r19<<<(MZ * H) / 256, 256, 0, stream>>>(hE, cE, egates, ys + (size_t)s * MZ * H);
  }

  gemm_ab_r19<1><<<dim3(128 / 64, (SL * MZ) / 64), 256, 0, stream>>>(ys, Wp, alphaA, betaA, SL * MZ, 128, H);

  prep_dec_r19<<<(GG * H) / 256, 256, 0, stream>>>(dWih, dWhh, dbih, dbhh,
                                                   WihHi, WihLo, WhhHi, WhhLo, bsum,
                                                   hD, h0Hi, h0Lo);

  sample_beta_r19<<<(RD * AR) / 256, 256, 0, stream>>>(alphaA, betaA, sig0Hi, sig0Lo, 0);

  // try persistent cooperative decoder; fall back to per-step loop on error
  const float* cInit = dInit + H;
  void* args[] = {
    (void*)&sig0Hi, (void*)&sig0Lo, (void*)&sig1Hi, (void*)&sig1Lo,
    (void*)&h0Hi, (void*)&h0Lo, (void*)&h1Hi, (void*)&h1Lo,
    (void*)&WihHi, (void*)&WihLo, (void*)&WhhHi, (void*)&WhhLo,
    (void*)&bsum, (void*)&hD, (void*)&cInit,
    (void*)&alphaA, (void*)&betaA
  };
  hipError_t cerr = hipLaunchCooperativeKernel((const void*)dec_persist_r19,
                                               dim3(1024), dim3(256), args, 0, stream);
  if (cerr != hipSuccess) {
    for (int s = 0; s < SL; ++s) {
      const unsigned short* sHi = (s & 1) ? sig1Hi : sig0Hi;
      const unsigned short* sLo = (s & 1) ? sig1Lo : sig0Lo;
      unsigned short* snHi = (s & 1) ? sig0Hi : sig1Hi;
      unsigned short* snLo = (s & 1) ? sig0Lo : sig1Lo;
      const unsigned short* hiIn = (s & 1) ? h1Hi : h0Hi;
      const unsigned short* loIn = (s & 1) ? h1Lo : h0Lo;
      unsigned short* hiOut = (s & 1) ? h0Hi : h1Hi;
      unsigned short* loOut = (s & 1) ? h0Lo : h1Lo;
      int nSamp = (s < SL - 1) ? SAMP_BLOCKS : 0;
      mfma_step_r19<<<nSamp + MFMA_BLOCKS, 256, 0, stream>>>(
          sHi, sLo, hiIn, loIn, WihHi, WihLo, WhhHi, WhhLo, bsum,
          hD, cD, hiOut, loOut, (s == SL - 1) ? 1 : 0,
          alphaA, betaA, snHi, snLo, s + 1, nSamp);
    }
  }

  gemm_ab_r19<0><<<dim3(H / 64, RD / 64), 256, 0, stream>>>(hD, Wo, logits, nullptr, RD, H, H);
  softmax_rows_r19<<<RD, 256, 0, stream>>>(logits, out);
}

// Round 20
// 5070.269 us; speedup vs baseline: 2.8162x; 2.8162x over previous
//
#include <hip/hip_runtime.h>
#include <cstdint>
#include <cstddef>

// ====================================================================
// PyroSimpleSpeakerListenerLSTM — Round 20.
// Cooperative/persistent ABANDONED (r19: grid.sync flushes the 8
// non-coherent XCD L2s -> 6.4GB refetch). Back to r17 per-step
// structure + XCD-aware block swizzle: the 16 ub-blocks sharing one
// mb's A-rows all land on one XCD (xcd = b&7). Pure index remap,
// math unchanged -> bit-identical output. Kernels _r20.
// ====================================================================

namespace {

constexpr int MZ = 512;
constexpr int EMB = 256;
constexpr int H = 512;
constexpr int SL = 32;
constexpr int BT = 16;
constexpr int AR = 64;
constexpr int GG = 4 * H;
constexpr int RD = BT * MZ;
constexpr int LROW = 36;     // padded LDS row (shorts): 72B
constexpr int SAMP_BLOCKS = 128;
constexpr int MFMA_BLOCKS = (H / 32) * (RD / 128);   // 1024

typedef float f32x4 __attribute__((ext_vector_type(4)));
typedef __bf16 bf16x8 __attribute__((ext_vector_type(8)));

struct KK { unsigned a, b; };

__host__ __device__ constexpr unsigned rotl32(unsigned v, int r) {
  return (v << r) | (v >> (32 - r));
}

__host__ __device__ constexpr KK tf(unsigned k0, unsigned k1, unsigned x0, unsigned x1) {
  unsigned k2 = k0 ^ k1 ^ 0x1BD11BDAu;
  x0 += k0; x1 += k1;
  x0 += x1; x1 = rotl32(x1,13); x1 ^= x0;
  x0 += x1; x1 = rotl32(x1,15); x1 ^= x0;
  x0 += x1; x1 = rotl32(x1,26); x1 ^= x0;
  x0 += x1; x1 = rotl32(x1, 6); x1 ^= x0;
  x0 += k1; x1 += k2 + 1u;
  x0 += x1; x1 = rotl32(x1,17); x1 ^= x0;
  x0 += x1; x1 = rotl32(x1,29); x1 ^= x0;
  x0 += x1; x1 = rotl32(x1,16); x1 ^= x0;
  x0 += x1; x1 = rotl32(x1,24); x1 ^= x0;
  x0 += k2; x1 += k0 + 2u;
  x0 += x1; x1 = rotl32(x1,13); x1 ^= x0;
  x0 += x1; x1 = rotl32(x1,15); x1 ^= x0;
  x0 += x1; x1 = rotl32(x1,26); x1 ^= x0;
  x0 += x1; x1 = rotl32(x1, 6); x1 ^= x0;
  x0 += k0; x1 += k1 + 3u;
  x0 += x1; x1 = rotl32(x1,17); x1 ^= x0;
  x0 += x1; x1 = rotl32(x1,29); x1 ^= x0;
  x0 += x1; x1 = rotl32(x1,16); x1 ^= x0;
  x0 += x1; x1 = rotl32(x1,24); x1 ^= x0;
  x0 += k1; x1 += k2 + 4u;
  x0 += x1; x1 = rotl32(x1,13); x1 ^= x0;
  x0 += x1; x1 = rotl32(x1,15); x1 ^= x0;
  x0 += x1; x1 = rotl32(x1,26); x1 ^= x0;
  x0 += x1; x1 = rotl32(x1, 6); x1 ^= x0;
  x0 += k2; x1 += k0 + 5u;
  return KK{x0, x1};
}

constexpr KK KEYA = tf(0u, 42u, 0u, 0u);
constexpr KK KEYB = tf(0u, 42u, 0u, 1u);

__device__ __forceinline__ void split2(KK k, KK& o0, KK& o1) {
  o0 = tf(k.a, k.b, 0u, 0u); o1 = tf(k.a, k.b, 0u, 1u);
}

__device__ __forceinline__ void split3(KK k, KK& o0, KK& o1, KK& o2) {
  o0 = tf(k.a, k.b, 0u, 0u); o1 = tf(k.a, k.b, 0u, 1u); o2 = tf(k.a, k.b, 0u, 2u);
}

__device__ __forceinline__ KK elem_key(KK gk, unsigned j) {
  return tf(gk.a, gk.b, 0u, j);
}

__device__ __forceinline__ unsigned rb32(KK k) {
  KK r = tf(k.a, k.b, 0u, 0u);
  return r.a ^ r.b;
}

__device__ __forceinline__ float u01_from_bits(unsigned bits) {
  return __uint_as_float(0x3F800000u | (bits >> 9)) - 1.0f;
}
__device__ __forceinline__ float uniform01(KK k) {
  return u01_from_bits(rb32(k));
}

__device__ float erfinv_xla(float x) {
  float xx = __fmul_rn(x, x);
  float w = -log1pf(-xx);
  float p;
  if (w < 5.0f) {
    w = __fsub_rn(w, 2.5f);
    p = 2.81022636e-08f;
    p = __fadd_rn(3.43273939e-07f, __fmul_rn(p, w));
    p = __fadd_rn(-3.5233877e-06f, __fmul_rn(p, w));
    p = __fadd_rn(-4.39150654e-06f, __fmul_rn(p, w));
    p = __fadd_rn(0.00021858087f, __fmul_rn(p, w));
    p = __fadd_rn(-0.00125372503f, __fmul_rn(p, w));
    p = __fadd_rn(-0.00417768164f, __fmul_rn(p, w));
    p = __fadd_rn(0.246640727f, __fmul_rn(p, w));
    p = __fadd_rn(1.50140941f, __fmul_rn(p, w));
  } else {
    w = __fsub_rn(__fsqrt_rn(w), 3.0f);
    p = -0.000200214257f;
    p = __fadd_rn(0.000100950558f, __fmul_rn(p, w));
    p = __fadd_rn(0.00134934322f, __fmul_rn(p, w));
    p = __fadd_rn(-0.00367342844f, __fmul_rn(p, w));
    p = __fadd_rn(0.00573950773f, __fmul_rn(p, w));
    p = __fadd_rn(-0.0076224613f, __fmul_rn(p, w));
    p = __fadd_rn(0.00943887047f, __fmul_rn(p, w));
    p = __fadd_rn(1.00167406f, __fmul_rn(p, w));
    p = __fadd_rn(2.83297682f, __fmul_rn(p, w));
  }
  return __fmul_rn(p, x);
}

__device__ __forceinline__ float normal_f(KK k) {
  float f = u01_from_bits(rb32(k));
  const float lo = __uint_as_float(0xBF7FFFFFu);
  float u = __fadd_rn(__fmul_rn(f, 2.0f), lo);
  u = fmaxf(lo, u);
  return __fmul_rn(__uint_as_float(0x3FB504F3u), erfinv_xla(u));
}

__device__ float loggamma_one(KK ekey, float alpha_orig) {
  KK key, sub;
  split2(ekey, key, sub);
  float u_boost = uniform01(sub);
  const bool boost = (alpha_orig >= 1.0f);
  const float al = boost ? alpha_orig : __fadd_rn(alpha_orig, 1.0f);
  const float third = (float)(1.0 / 3.0);
  const float d = __fsub_rn(al, third);
  const float c = __fdiv_rn(third, __fsqrt_rn(d));
  float X, V;
  for (;;) {
    KK nk, xk, uk;
    split3(key, nk, xk, uk);
    key = nk;
    float x, v;
    KK kk = xk;
    do {
      KK k2, ns;
      split2(kk, k2, ns);
      kk = k2;
      x = normal_f(ns);
      v = __fadd_rn(1.0f, __fmul_rn(x, c));
    } while (v <= 0.0f);
    X = __fmul_rn(x, x);
    V = __fmul_rn(__fmul_rn(v, v), v);
    float U = uniform01(uk);
    float sq = __fsub_rn(1.0f, __fmul_rn(0.0331f, __fmul_rn(X, X)));
    if (U < sq) break;
    float rhs = __fadd_rn(__fmul_rn(0.5f, X),
                          __fmul_rn(d, __fadd_rn(__fsub_rn(1.0f, V), logf(V))));
    if (logf(U) < rhs) break;
  }
  float ls = __fadd_rn(logf(d), logf(V));
  if (!boost)
    ls = __fadd_rn(ls, __fdiv_rn(log1pf(-u_boost), alpha_orig));
  return ls;
}

__device__ __forceinline__ float sigm(float x) { return 1.0f / (1.0f + expf(-x)); }

__device__ __forceinline__ unsigned short f2bf(float x) {
  unsigned u = __float_as_uint(x);
  unsigned r = (u + 0x7fffu + ((u >> 16) & 1u)) >> 16;
  return (unsigned short)r;
}
__device__ __forceinline__ float bf2f(unsigned short h) {
  return __uint_as_float(((unsigned)h) << 16);
}
__device__ __forceinline__ void split_bf(float x, unsigned short& hi, unsigned short& lo) {
  hi = f2bf(x);
  lo = f2bf(x - bf2f(hi));
}

__device__ __forceinline__ void beta_sample(const float* __restrict__ alphaA,
                                            const float* __restrict__ betaA,
                                            unsigned short* __restrict__ sigHi,
                                            unsigned short* __restrict__ sigLo,
                                            unsigned idx, int s) {
  unsigned r = idx >> 6;
  unsigned j = idx & 63u;
  unsigned b = r >> 9;
  unsigned m = r & 511u;
  size_t ab = ((size_t)s * MZ + m) * AR + j;
  float alpha = alphaA[ab];
  float beta = betaA[ab];
  unsigned jl = ((b * 32u + (unsigned)s) * 512u + m) * 64u + j;
  float lga = loggamma_one(elem_key(KEYA, jl), alpha);
  float lgb = loggamma_one(elem_key(KEYB, jl), beta);
  float lm = fmaxf(lga, lgb);
  float ea = expf(__fsub_rn(lga, lm));
  float eb = expf(__fsub_rn(lgb, lm));
  float sv = __fdiv_rn(ea, __fadd_rn(ea, eb));
  split_bf(sv, sigHi[idx], sigLo[idx]);
}

} // namespace

// ----------------------------- kernels ------------------------------

__global__ __launch_bounds__(256) void fill_sentinel_r20(float* o, int n) {
  int i = blockIdx.x * 256 + threadIdx.x;
  if (i < n) o[i] = 12345.0f;
}

__global__ __launch_bounds__(256) void init_states_r20(const float* __restrict__ encI,
                                                       const float* __restrict__ decI,
                                                       float* __restrict__ hE, float* __restrict__ cE,
                                                       float* __restrict__ hD, float* __restrict__ cD) {
  int idx = blockIdx.x * 256 + threadIdx.x;
  int u = idx & (H - 1);
  if (idx < MZ * H) { hE[idx] = encI[u]; cE[idx] = encI[H + u]; }
  hD[idx] = decI[u]; cD[idx] = decI[H + u];
}

__global__ __launch_bounds__(256) void prep_dec_r20(const float* __restrict__ Wih,
                                                    const float* __restrict__ Whh,
                                                    const float* __restrict__ b1,
                                                    const float* __restrict__ b2,
                                                    unsigned short* __restrict__ WihHi,
                                                    unsigned short* __restrict__ WihLo,
                                                    unsigned short* __restrict__ WhhHi,
                                                    unsigned short* __restrict__ WhhLo,
                                                    float* __restrict__ bsum,
                                                    const float* __restrict__ hD,
                                                    unsigned short* __restrict__ hHi,
                                                    unsigned short* __restrict__ hLo) {
  int idx = blockIdx.x * 256 + threadIdx.x;   // GG*H threads
  split_bf(Whh[idx], WhhHi[idx], WhhLo[idx]);
  if (idx < GG * AR) split_bf(Wih[idx], WihHi[idx], WihLo[idx]);
  if (idx < GG) bsum[idx] = b1[idx] + b2[idx];
  for (int i = idx; i < RD * H; i += GG * H) split_bf(hD[i], hHi[i], hLo[i]);
}

template <int MODE>
__global__ __launch_bounds__(256) void gemm_abt_r20(const float* __restrict__ A,
                                                    const float* __restrict__ B,
                                                    float* __restrict__ C,
                                                    const float* __restrict__ X1,
                                                    const float* __restrict__ X2,
                                                    int M, int N, int K) {
  __shared__ float As[16][68];
  __shared__ float Bs[16][68];
  int tid = threadIdx.x;
  int tx = tid & 15, ty = tid >> 4;
  int n0 = blockIdx.x * 64, m0 = blockIdx.y * 64;
  int lr = tid >> 2, lk4 = (tid & 3) * 4;
  float acc[4][4] = {};
  for (int k0 = 0; k0 < K; k0 += 16) {
    float4 a4 = *reinterpret_cast<const float4*>(A + (size_t)(m0 + lr) * K + k0 + lk4);
    float4 b4 = *reinterpret_cast<const float4*>(B + (size_t)(n0 + lr) * K + k0 + lk4);
    __syncthreads();
    As[lk4 + 0][lr] = a4.x; As[lk4 + 1][lr] = a4.y; As[lk4 + 2][lr] = a4.z; As[lk4 + 3][lr] = a4.w;
    Bs[lk4 + 0][lr] = b4.x; Bs[lk4 + 1][lr] = b4.y; Bs[lk4 + 2][lr] = b4.z; Bs[lk4 + 3][lr] = b4.w;
    __syncthreads();
#pragma unroll
    for (int k = 0; k < 16; ++k) {
      float av[4], bv[4];
#pragma unroll
      for (int i = 0; i < 4; ++i) av[i] = As[k][ty * 4 + i];
#pragma unroll
      for (int j = 0; j < 4; ++j) bv[j] = Bs[k][tx * 4 + j];
#pragma unroll
      for (int i = 0; i < 4; ++i)
#pragma unroll
        for (int j = 0; j < 4; ++j) acc[i][j] = fmaf(av[i], bv[j], acc[i][j]);
    }
  }
#pragma unroll
  for (int i = 0; i < 4; ++i) {
    int m = m0 + ty * 4 + i;
#pragma unroll
    for (int j = 0; j < 4; ++j) {
      int n = n0 + tx * 4 + j;
      float v = acc[i][j];
      if (MODE == 1) v += X1[n] + X2[n];
      if (MODE == 2) v += X1[(size_t)m * N + n];
      C[(size_t)m * N + n] = v;
    }
  }
}

// --- merged decoder step: sampler blocks + XCD-swizzled mfma+LSTM blocks ---
__global__ __launch_bounds__(256) void mfma_step_r20(
    const unsigned short* __restrict__ sigHi, const unsigned short* __restrict__ sigLo,
    const unsigned short* __restrict__ hHiIn, const unsigned short* __restrict__ hLoIn,
    const unsigned short* __restrict__ WihHi, const unsigned short* __restrict__ WihLo,
    const unsigned short* __restrict__ WhhHi, const unsigned short* __restrict__ WhhLo,
    const float* __restrict__ bsum,
    float* __restrict__ hD, float* __restrict__ cD,
    unsigned short* __restrict__ hHiOut, unsigned short* __restrict__ hLoOut,
    int writeHF,
    const float* __restrict__ alphaA, const float* __restrict__ betaA,
    unsigned short* __restrict__ sigHiNext, unsigned short* __restrict__ sigLoNext,
    int sNext, int nSamp) {
  __shared__ __align__(16) unsigned short AhiS[128 * LROW];
  __shared__ __align__(16) unsigned short AloS[128 * LROW];
  __shared__ __align__(16) unsigned short BhiS[128 * LROW];
  __shared__ __align__(16) unsigned short BloS[128 * LROW];
  int bid = blockIdx.x;
  if (bid < nSamp) {
    unsigned base = bid * 256 + threadIdx.x;
    unsigned stride = (unsigned)nSamp * 256;
    for (unsigned idx = base; idx < (unsigned)(RD * AR); idx += stride)
      beta_sample(alphaA, betaA, sigHiNext, sigLoNext, idx, sNext);
    return;
  }
  bid -= nSamp;   // 0..1023; nSamp multiple of 8 keeps XCD parity
  // XCD-aware swizzle: all 16 ub-blocks of one mb land on one XCD (bid&7)
  int xcd = bid & 7, idxx = bid >> 3;
  int mb = xcd * 8 + (idxx >> 4);
  int ub = idxx & 15;
  int mbBase = mb * 128;
  int ubBase = ub * 32;
  int tid = threadIdx.x;
  int lane = tid & 63, wid = tid >> 6;
  int wr = wid >> 1, wu = wid & 1;
  int lr = lane & 15;
  int lk = (lane >> 4) * 8;
  int srow = tid >> 2;
  int scol = (tid & 3) * 8;
  f32x4 acc[4][4] = {};
  for (int ks = 0; ks < 18; ++ks) {
    int k0 = ks * 32;
    const unsigned short* Ah; const unsigned short* Al;
    const unsigned short* Bh; const unsigned short* Bl;
    int K, kk;
    if (k0 < 64) { Ah = sigHi; Al = sigLo; Bh = WihHi; Bl = WihLo; K = AR; kk = k0; }
    else         { Ah = hHiIn; Al = hLoIn; Bh = WhhHi; Bl = WhhLo; K = H;  kk = k0 - 64; }
    __syncthreads();
#pragma unroll
    for (int q = 0; q < 2; ++q) {
      int row = q * 64 + srow;
      size_t asrc = (size_t)(mbBase + row) * K + kk + scol;
      int g = row >> 5, uu = row & 31;
      size_t bsrc = (size_t)(g * 512 + ubBase + uu) * K + kk + scol;
      int ldst = row * LROW + scol;
      *reinterpret_cast<bf16x8*>(&AhiS[ldst]) = *reinterpret_cast<const bf16x8*>(Ah + asrc);
      *reinterpret_cast<bf16x8*>(&AloS[ldst]) = *reinterpret_cast<const bf16x8*>(Al + asrc);
      *reinterpret_cast<bf16x8*>(&BhiS[ldst]) = *reinterpret_cast<const bf16x8*>(Bh + bsrc);
      *reinterpret_cast<bf16x8*>(&BloS[ldst]) = *reinterpret_cast<const bf16x8*>(Bl + bsrc);
    }
    __syncthreads();
    bf16x8 ah[4], al[4], bh[4], bl[4];
#pragma unroll
    for (int f = 0; f < 4; ++f) {
      int arow = wr * 64 + f * 16 + lr;
      ah[f] = *reinterpret_cast<const bf16x8*>(&AhiS[arow * LROW + lk]);
      al[f] = *reinterpret_cast<const bf16x8*>(&AloS[arow * LROW + lk]);
      int brow = f * 32 + wu * 16 + lr;
      bh[f] = *reinterpret_cast<const bf16x8*>(&BhiS[brow * LROW + lk]);
      bl[f] = *reinterpret_cast<const bf16x8*>(&BloS[brow * LROW + lk]);
    }
#pragma unroll
    for (int i = 0; i < 4; ++i)
#pragma unroll
      for (int g = 0; g < 4; ++g) {
        acc[i][g] = __builtin_amdgcn_mfma_f32_16x16x32_bf16(ah[i], bh[g], acc[i][g], 0, 0, 0);
        acc[i][g] = __builtin_amdgcn_mfma_f32_16x16x32_bf16(ah[i], bl[g], acc[i][g], 0, 0, 0);
        acc[i][g] = __builtin_amdgcn_mfma_f32_16x16x32_bf16(al[i], bh[g], acc[i][g], 0, 0, 0);
      }
  }
  int m0 = mbBase + wr * 64;
  int crow = (lane >> 4) * 4;
  int u = ubBase + wu * 16 + (lane & 15);
  float bi = bsum[u], bff = bsum[u + 512], bg = bsum[u + 1024], bo = bsum[u + 1536];
#pragma unroll
  for (int i = 0; i < 4; ++i) {
#pragma unroll
    for (int r = 0; r < 4; ++r) {
      int m = m0 + i * 16 + crow + r;
      size_t idx = (size_t)m * H + u;
      float gi = acc[i][0][r] + bi;
      float gf = acc[i][1][r] + bff;
      float gg = acc[i][2][r] + bg;
      float go = acc[i][3][r] + bo;
      float cn = sigm(gf) * cD[idx] + sigm(gi) * tanhf(gg);
      float hn = sigm(go) * tanhf(cn);
      cD[idx] = cn;
      if (writeHF) hD[idx] = hn;
      split_bf(hn, hHiOut[idx], hLoOut[idx]);
    }
  }
}

template <int EPI>
__global__ __launch_bounds__(256) void gemm_ab_r20(const float* __restrict__ A,
                                                   const float* __restrict__ B,
                                                   float* __restrict__ C0,
                                                   float* __restrict__ C1,
                                                   int M, int N, int K) {
  __shared__ float As[16][68];
  __shared__ float Bs[16][68];
  int tid = threadIdx.x;
  int tx = tid & 15, ty = tid >> 4;
  int n0 = blockIdx.x * 64, m0 = blockIdx.y * 64;
  int lr = tid >> 2, lk4 = (tid & 3) * 4;
  int bk = tid >> 4, bn4 = (tid & 15) * 4;
  float acc[4][4] = {};
  for (int k0 = 0; k0 < K; k0 += 16) {
    float4 a4 = *reinterpret_cast<const float4*>(A + (size_t)(m0 + lr) * K + k0 + lk4);
    float4 b4 = *reinterpret_cast<const float4*>(B + (size_t)(k0 + bk) * N + n0 + bn4);
    __syncthreads();
    As[lk4 + 0][lr] = a4.x; As[lk4 + 1][lr] = a4.y; As[lk4 + 2][lr] = a4.z; As[lk4 + 3][lr] = a4.w;
    *reinterpret_cast<float4*>(&Bs[bk][bn4]) = b4;
    __syncthreads();
#pragma unroll
    for (int k = 0; k < 16; ++k) {
      float av[4], bv[4];
#pragma unroll
      for (int i = 0; i < 4; ++i) av[i] = As[k][ty * 4 + i];
#pragma unroll
      for (int j = 0; j < 4; ++j) bv[j] = Bs[k][tx * 4 + j];
#pragma unroll
      for (int i = 0; i < 4; ++i)
#pragma unroll
        for (int j = 0; j < 4; ++j) acc[i][j] = fmaf(av[i], bv[j], acc[i][j]);
    }
  }
#pragma unroll
  for (int i = 0; i < 4; ++i) {
    size_t m = (size_t)(m0 + ty * 4 + i);
#pragma unroll
    for (int j = 0; j < 4; ++j) {
      int n = n0 + tx * 4 + j;
      float v = acc[i][j];
      if (EPI == 0) {
        C0[m * N + n] = v;
      } else {
        float sp = fmaxf(v, 0.0f) + log1pf(expf(-fabsf(v)));
        if (n & 1) C1[m * (N / 2) + (n >> 1)] = sp;
        else       C0[m * (N / 2) + (n >> 1)] = sp;
      }
    }
  }
}

__global__ __launch_bounds__(256) void lstm_update_r20(float* __restrict__ h, float* __restrict__ c,
                                                       const float* __restrict__ gates,
                                                       float* __restrict__ ysOut) {
  int idx = blockIdx.x * 256 + threadIdx.x;
  int r = idx >> 9, u = idx & (H - 1);
  const float* g = gates + (size_t)r * GG;
  float gi = g[u], gf = g[u + H], gg = g[u + 2 * H], go = g[u + 3 * H];
  float cn = sigm(gf) * c[idx] + sigm(gi) * tanhf(gg);
  float hn = sigm(go) * tanhf(cn);
  c[idx] = cn; h[idx] = hn;
  if (ysOut) ysOut[idx] = hn;
}

__global__ __launch_bounds__(256) void sample_beta_r20(const float* __restrict__ alphaA,
                                                       const float* __restrict__ betaA,
                                                       unsigned short* __restrict__ sigHi,
                                                       unsigned short* __restrict__ sigLo,
                                                       int s) {
  unsigned idx = blockIdx.x * 256 + threadIdx.x;
  beta_sample(alphaA, betaA, sigHi, sigLo, idx, s);
}

__global__ __launch_bounds__(256) void softmax_rows_r20(const float* __restrict__ L,
                                                        float* __restrict__ O) {
  __shared__ float red[8];
  int r = blockIdx.x;
  const float* row = L + (size_t)r * H;
  int t = threadIdx.x;
  float a = row[t], b = row[t + 256];
  float m = fmaxf(a, b);
#pragma unroll
  for (int o = 1; o < 64; o <<= 1) m = fmaxf(m, __shfl_xor(m, o));
  if ((t & 63) == 0) red[t >> 6] = m;
  __syncthreads();
  m = fmaxf(fmaxf(red[0], red[1]), fmaxf(red[2], red[3]));
  float e0 = expf(a - m), e1 = expf(b - m);
  float s = e0 + e1;
#pragma unroll
  for (int o = 1; o < 64; o <<= 1) s += __shfl_xor(s, o);
  if ((t & 63) == 0) red[4 + (t >> 6)] = s;
  __syncthreads();
  s = red[4] + red[5] + red[6] + red[7];
  O[(size_t)r * H + t] = e0 / s;
  O[(size_t)r * H + t + 256] = e1 / s;
}

// ----------------------------- launcher -----------------------------

extern "C" void kernel_launch(void* const* d_in, const int* in_sizes, int n_in,
                              void* d_out, int out_size, void* d_ws, size_t ws_size,
                              hipStream_t stream) {
  (void)in_sizes; (void)n_in;
  const float* embedding = (const float*)d_in[2];
  const float* eWih = (const float*)d_in[3];
  const float* eWhh = (const float*)d_in[4];
  const float* ebih = (const float*)d_in[5];
  const float* ebhh = (const float*)d_in[6];
  const float* eInit = (const float*)d_in[7];
  const float* dWih = (const float*)d_in[8];
  const float* dWhh = (const float*)d_in[9];
  const float* dbih = (const float*)d_in[10];
  const float* dbhh = (const float*)d_in[11];
  const float* dInit = (const float*)d_in[12];
  const float* Wp = (const float*)d_in[13];
  const float* Wo = (const float*)d_in[14];
  float* out = (float*)d_out;
  float* w = (float*)d_ws;

  size_t o = 0;
  float* xW     = w + o; o += (size_t)MZ * GG;
  float* hE     = w + o; o += (size_t)MZ * H;
  float* cE     = w + o; o += (size_t)MZ * H;
  float* ys     = w + o; o += (size_t)SL * MZ * H;
  float* alphaA = w + o; o += (size_t)SL * MZ * AR;
  float* betaA  = w + o; o += (size_t)SL * MZ * AR;
  float* hD     = w + o; o += (size_t)RD * H;
  float* cD     = w + o; o += (size_t)RD * H;
  float* regB   = w + o; o += (size_t)RD * GG / 4;
  float* logits = w + o; o += (size_t)RD * H;
  float* sig1F  = w + o; o += (size_t)RD * AR;
  if (ws_size < o * sizeof(float)) {
    fill_sentinel_r20<<<(out_size + 255) / 256, 256, 0, stream>>>(out, out_size);
    return;
  }

  unsigned short* sig0Hi = (unsigned short*)ys;
  unsigned short* sig0Lo = sig0Hi + (size_t)RD * AR;
  unsigned short* h0Hi  = sig0Lo + (size_t)RD * AR;
  unsigned short* h0Lo  = h0Hi + (size_t)RD * H;
  unsigned short* WihHi = h0Lo + (size_t)RD * H;
  unsigned short* WihLo = WihHi + (size_t)GG * AR;
  unsigned short* WhhHi = WihLo + (size_t)GG * AR;
  unsigned short* WhhLo = WhhHi + (size_t)GG * H;
  float* bsum = (float*)(WhhLo + (size_t)GG * H);
  unsigned short* h1Hi = (unsigned short*)regB;
  unsigned short* h1Lo = h1Hi + (size_t)RD * H;
  unsigned short* sig1Hi = (unsigned short*)sig1F;
  unsigned short* sig1Lo = sig1Hi + (size_t)RD * AR;

  init_states_r20<<<(RD * H) / 256, 256, 0, stream>>>(eInit, dInit, hE, cE, hD, cD);

  float* egates = logits;
  gemm_abt_r20<1><<<dim3(GG / 64, MZ / 64), 256, 0, stream>>>(embedding, eWih, xW, ebih, ebhh, MZ, GG, EMB);
  for (int s = 0; s < SL; ++s) {
    gemm_abt_r20<2><<<dim3(GG / 64, MZ / 64), 256, 0, stream>>>(hE, eWhh, egates, xW, nullptr, MZ, GG, H);
    lstm_update_r20<<<(MZ * H) / 256, 256, 0, stream>>>(hE, cE, egates, ys + (size_t)s * MZ * H);
  }

  gemm_ab_r20<1><<<dim3(128 / 64, (SL * MZ) / 64), 256, 0, stream>>>(ys, Wp, alphaA, betaA, SL * MZ, 128, H);

  prep_dec_r20<<<(GG * H) / 256, 256, 0, stream>>>(dWih, dWhh, dbih, dbhh,
                                                   WihHi, WihLo, WhhHi, WhhLo, bsum,
                                                   hD, h0Hi, h0Lo);

  sample_beta_r20<<<(RD * AR) / 256, 256, 0, stream>>>(alphaA, betaA, sig0Hi, sig0Lo, 0);

  for (int s = 0; s < SL; ++s) {
    const unsigned short* sHi = (s & 1) ? sig1Hi : sig0Hi;
    const unsigned short* sLo = (s & 1) ? sig1Lo : sig0Lo;
    unsigned short* snHi = (s & 1) ? sig0Hi : sig1Hi;
    unsigned short* snLo = (s & 1) ? sig0Lo : sig1Lo;
    const unsigned short* hiIn = (s & 1) ? h1Hi : h0Hi;
    const unsigned short* loIn = (s & 1) ? h1Lo : h0Lo;
    unsigned short* hiOut = (s & 1) ? h0Hi : h1Hi;
    unsigned short* loOut = (s & 1) ? h0Lo : h1Lo;
    int nSamp = (s < SL - 1) ? SAMP_BLOCKS : 0;
    mfma_step_r20<<<nSamp + MFMA_BLOCKS, 256, 0, stream>>>(
        sHi, sLo, hiIn, loIn, WihHi, WihLo, WhhHi, WhhLo, bsum,
        hD, cD, hiOut, loOut, (s == SL - 1) ? 1 : 0,
        alphaA, betaA, snHi, snLo, s + 1, nSamp);
  }

  gemm_ab_r20<0><<<dim3(H / 64, RD / 64), 256, 0, stream>>>(hD, Wo, logits, nullptr, RD, H, H);
  softmax_rows_r20<<<RD, 256, 0, stream>>>(logits, out);
}